// Round 2
// baseline (82.117 us; speedup 1.0000x reference)
//
#include <hip/hip_runtime.h>
#include <math.h>

#define NW 599
#define NRR 598
#define BLK 256

__device__ inline float wave_sum(float v) {
#pragma unroll
  for (int o = 32; o > 0; o >>= 1) v += __shfl_down(v, o);
  return v;
}

// all 256 threads must call; returns full-block sum broadcast to all threads
__device__ inline float block_sum(float v, float* scratch, int tid) {
  v = wave_sum(v);
  if ((tid & 63) == 0) scratch[tid >> 6] = v;
  __syncthreads();
  float r = scratch[0] + scratch[1] + scratch[2] + scratch[3];
  __syncthreads();
  return r;
}

__global__ __launch_bounds__(BLK) void prv_kernel(
    const float* __restrict__ x, const float* __restrict__ W1,
    const float* __restrict__ b1, const float* __restrict__ W2,
    const float* __restrict__ b2, const float* __restrict__ gamma,
    const float* __restrict__ beta, float* __restrict__ out, int S) {
  __shared__ float s_row[9000];
  __shared__ float s_peak[NW];
  __shared__ float s_rr[NRR];
  __shared__ float s_red[96];
  __shared__ float s_pow[12];
  __shared__ float s_feat[5];
  __shared__ float s_h1[64];
  __shared__ float s_scr[4];

  const int b = blockIdx.x;
  const int tid = threadIdx.x;
  const float* __restrict__ xrow = x + (size_t)b * S;

  // ---- stage row to LDS (coalesced float4: 9000 = 2250 * 4) ----
  const float4* xr4 = (const float4*)xrow;
  float4* sr4 = (float4*)s_row;
  for (int i = tid; i < S / 4; i += BLK) sr4[i] = xr4[i];
  __syncthreads();

  // ---- per-window softmax-expected peak ----
  for (int w = tid; w < NW; w += BLK) {
    const float* p = s_row + w * 15;
    float m = p[0];
#pragma unroll
    for (int j = 1; j < 30; ++j) m = fmaxf(m, p[j]);
    float se = 0.f, we = 0.f;
#pragma unroll
    for (int j = 0; j < 30; ++j) {
      float e = __expf((p[j] - m) * 10.0f);  // temp = 0.1
      se += e;
      we += (float)j * e;
    }
    s_peak[w] = we / se + (float)(w * 15);
  }
  __syncthreads();

  // ---- rr series ----
  for (int i = tid; i < NRR; i += BLK)
    s_rr[i] = (s_peak[i + 1] - s_peak[i]) * (1.0f / 30.0f);
  __syncthreads();

  // ---- mean ----
  float v = 0.f;
  for (int i = tid; i < NRR; i += BLK) v += s_rr[i];
  const float mean_rr = block_sum(v, s_scr, tid) * (1.0f / (float)NRR);

  // ---- sdnn (ddof=1, two-pass) + rmssd ----
  float sq = 0.f, d2 = 0.f;
  for (int i = tid; i < NRR; i += BLK) {
    float r = s_rr[i] - mean_rr;
    sq += r * r;
    if (i < NRR - 1) {
      float df = s_rr[i + 1] - s_rr[i];
      d2 += df * df;
    }
  }
  const float var_rr = block_sum(sq, s_scr, tid) * (1.0f / (float)(NRR - 1));
  const float msd = block_sum(d2, s_scr, tid) * (1.0f / (float)(NRR - 1));
  const float sdnn = sqrtf(var_rr);
  const float rmssd = sqrtf(msd + 1e-6f);

  // ---- sparse DFT: bins k = 2..13 of rfft(rr, n=1024) ----
  float re[12], im[12];
#pragma unroll
  for (int k = 0; k < 12; ++k) { re[k] = 0.f; im[k] = 0.f; }
  for (int n = tid; n < NRR; n += BLK) {
    float rv = s_rr[n];
#pragma unroll
    for (int kk = 0; kk < 12; ++kk) {
      int m = ((kk + 2) * n) & 1023;               // exact integer phase
      float ang = (float)m * 6.13592315154256491e-3f;  // 2*pi/1024
      float sn, cs;
      __sincosf(ang, &sn, &cs);
      re[kk] = fmaf(rv, cs, re[kk]);
      im[kk] = fmaf(-rv, sn, im[kk]);
    }
  }
  const int wid = tid >> 6, lane = tid & 63;
#pragma unroll
  for (int kk = 0; kk < 12; ++kk) {
    float r = wave_sum(re[kk]);
    float i2 = wave_sum(im[kk]);
    if (lane == 0) {
      s_red[wid * 24 + kk] = r;
      s_red[wid * 24 + 12 + kk] = i2;
    }
  }
  __syncthreads();
  if (tid < 12) {
    float r = s_red[tid] + s_red[24 + tid] + s_red[48 + tid] + s_red[72 + tid];
    float i2 =
        s_red[12 + tid] + s_red[36 + tid] + s_red[60 + tid] + s_red[84 + tid];
    s_pow[tid] = r * r + i2 * i2;
  }
  __syncthreads();
  if (tid == 0) {
    float lf = s_pow[0] + s_pow[1] + s_pow[2] + s_pow[3];  // k=2..5
    float hf = 0.f;
#pragma unroll
    for (int k = 4; k < 12; ++k) hf += s_pow[k];  // k=6..13
    s_feat[0] = mean_rr;
    s_feat[1] = rmssd;
    s_feat[2] = sdnn;
    s_feat[3] = lf;
    s_feat[4] = hf;
  }
  __syncthreads();

  // ---- MLP layer 1: (5) @ (5,64) + b1, relu ----
  if (tid < 64) {
    float acc = b1[tid];
#pragma unroll
    for (int i = 0; i < 5; ++i) acc = fmaf(s_feat[i], W1[i * 64 + tid], acc);
    s_h1[tid] = fmaxf(acc, 0.f);
  }
  __syncthreads();

  // ---- MLP layer 2: (64) @ (64,128) + b2 ----
  float h2 = 0.f;
  if (tid < 128) {
    float acc = b2[tid];
#pragma unroll 8
    for (int i = 0; i < 64; ++i) acc = fmaf(s_h1[i], W2[i * 128 + tid], acc);
    h2 = acc;
  }

  // ---- LayerNorm over 128 (two-pass) ----
  float sv = (tid < 128) ? h2 : 0.f;
  const float mu = block_sum(sv, s_scr, tid) * (1.0f / 128.0f);
  float dv = (tid < 128) ? (h2 - mu) * (h2 - mu) : 0.f;
  const float var = block_sum(dv, s_scr, tid) * (1.0f / 128.0f);
  if (tid < 128) {
    out[(size_t)b * 128 + tid] =
        (h2 - mu) * rsqrtf(var + 1e-5f) * gamma[tid] + beta[tid];
  }
}

extern "C" void kernel_launch(void* const* d_in, const int* in_sizes, int n_in,
                              void* d_out, int out_size, void* d_ws,
                              size_t ws_size, hipStream_t stream) {
  const float* x = (const float*)d_in[0];
  const float* W1 = (const float*)d_in[1];
  const float* b1 = (const float*)d_in[2];
  const float* W2 = (const float*)d_in[3];
  const float* b2 = (const float*)d_in[4];
  const float* gamma = (const float*)d_in[5];
  const float* beta = (const float*)d_in[6];
  float* out = (float*)d_out;

  const int S = 9000;
  const int B = in_sizes[0] / S;
  prv_kernel<<<B, BLK, 0, stream>>>(x, W1, b1, W2, b2, gamma, beta, out, S);
}

// Round 3
// 50.012 us; speedup vs baseline: 1.6419x; 1.6419x over previous
//
#include <hip/hip_runtime.h>
#include <math.h>

#define S_LEN 9000
#define NW 599
#define NRR 598
#define PK_STRIDE 600
#define CHUNK 200  // windows per block in peaks_kernel (3 balanced chunks)
#define BLK 256

// ---------- small helpers ----------
__device__ inline float wave_allsum(float v) {
#pragma unroll
  for (int o = 32; o > 0; o >>= 1) v += __shfl_xor(v, o);
  return v;
}

__device__ inline float wave_sum(float v) {
#pragma unroll
  for (int o = 32; o > 0; o >>= 1) v += __shfl_down(v, o);
  return v;
}

__device__ inline float block_sum(float v, float* scratch, int tid) {
  v = wave_sum(v);
  if ((tid & 63) == 0) scratch[tid >> 6] = v;
  __syncthreads();
  float r = scratch[0] + scratch[1] + scratch[2] + scratch[3];
  __syncthreads();
  return r;
}

// ================= kernel A: per-window softargmax peaks =================
// grid = (3, B). Chunk c covers windows [200c, 200c+nw). Window w reads
// x[15w .. 15w+30) -> local LDS offset 15*tid (stride-15 odd => conflict-free).
__global__ __launch_bounds__(256, 8) void peaks_kernel(
    const float* __restrict__ x, float* __restrict__ pk) {
  __shared__ float s[3024];
  const int c = blockIdx.x;
  const int row = blockIdx.y;
  const int tid = threadIdx.x;
  const int nw = min(NW - c * CHUNK, CHUNK);
  const int nf4 = (c < 2) ? 754 : 750;  // floats staged / 4
  const float4* src = (const float4*)(x + (size_t)row * S_LEN) + 750 * c;
  float4* dst = (float4*)s;
  for (int i = tid; i < nf4; i += 256) dst[i] = src[i];
  __syncthreads();
  if (tid < nw) {
    const float* p = s + 15 * tid;
    float m = p[0];
#pragma unroll
    for (int j = 1; j < 30; ++j) m = fmaxf(m, p[j]);
    float se = 0.f, we = 0.f;
#pragma unroll
    for (int j = 0; j < 30; ++j) {
      float e = __expf((p[j] - m) * 10.0f);  // temp = 0.1
      se += e;
      we += (float)j * e;
    }
    const int w = c * CHUNK + tid;
    pk[(size_t)row * PK_STRIDE + w] = we / se + 15.0f * (float)w;
  }
}

// ================= kernel B: per-row features + MLP + LN =================
// one wave per row, 4 rows per block; all reductions are wave butterflies.
__global__ __launch_bounds__(256, 4) void feat_kernel(
    const float* __restrict__ pk, const float* __restrict__ W1,
    const float* __restrict__ b1, const float* __restrict__ W2,
    const float* __restrict__ b2, const float* __restrict__ gamma,
    const float* __restrict__ beta, float* __restrict__ out, int nrows) {
  __shared__ float s_pk[4][PK_STRIDE];
  __shared__ float s_rr[4][NRR];
  const int tid = threadIdx.x;
  const int wid = tid >> 6, lane = tid & 63;
  const int row = blockIdx.x * 4 + wid;
  const bool act = row < nrows;

  if (act)
    for (int n = lane; n < NW; n += 64) s_pk[wid][n] = pk[(size_t)row * PK_STRIDE + n];
  __syncthreads();
  if (act)
    for (int n = lane; n < NRR; n += 64)
      s_rr[wid][n] = (s_pk[wid][n + 1] - s_pk[wid][n]) * (1.0f / 30.0f);
  __syncthreads();

  // mean
  float v = 0.f;
  if (act)
    for (int n = lane; n < NRR; n += 64) v += s_rr[wid][n];
  const float mean_rr = wave_allsum(v) * (1.0f / (float)NRR);

  // sdnn (ddof=1) + rmssd
  float sq = 0.f, d2 = 0.f;
  if (act)
    for (int n = lane; n < NRR; n += 64) {
      float r = s_rr[wid][n] - mean_rr;
      sq += r * r;
      if (n < NRR - 1) {
        float df = s_rr[wid][n + 1] - s_rr[wid][n];
        d2 += df * df;
      }
    }
  const float sdnn = sqrtf(wave_allsum(sq) * (1.0f / (float)(NRR - 1)));
  const float rmssd = sqrtf(wave_allsum(d2) * (1.0f / (float)(NRR - 1)) + 1e-6f);

  // sparse DFT: rfft(rr, 1024) bins k=2..13 (LF: 2..5, HF: 6..13)
  float re[12], im[12];
#pragma unroll
  for (int k = 0; k < 12; ++k) { re[k] = 0.f; im[k] = 0.f; }
  if (act)
    for (int n = lane; n < NRR; n += 64) {
      float rv = s_rr[wid][n];
#pragma unroll
      for (int kk = 0; kk < 12; ++kk) {
        int m = ((kk + 2) * n) & 1023;                   // exact phase
        float ang = (float)m * 6.13592315154256491e-3f;  // 2*pi/1024
        float sn, cs;
        __sincosf(ang, &sn, &cs);
        re[kk] = fmaf(rv, cs, re[kk]);
        im[kk] = fmaf(-rv, sn, im[kk]);
      }
    }
  float lf = 0.f, hf = 0.f;
#pragma unroll
  for (int kk = 0; kk < 12; ++kk) {
    float r = wave_allsum(re[kk]);
    float i2 = wave_allsum(im[kk]);
    float pw = r * r + i2 * i2;
    if (kk < 4) lf += pw; else hf += pw;
  }

  // MLP layer 1 (5 -> 64): lane computes h1[lane]
  float h1 = b1[lane];
  h1 = fmaf(mean_rr, W1[lane], h1);
  h1 = fmaf(rmssd, W1[64 + lane], h1);
  h1 = fmaf(sdnn, W1[128 + lane], h1);
  h1 = fmaf(lf, W1[192 + lane], h1);
  h1 = fmaf(hf, W1[256 + lane], h1);
  h1 = fmaxf(h1, 0.f);

  // MLP layer 2 (64 -> 128): lane computes outputs lane and lane+64
  float a0 = b2[lane], a1 = b2[64 + lane];
#pragma unroll 8
  for (int i = 0; i < 64; ++i) {
    float hv = __shfl(h1, i);
    a0 = fmaf(hv, W2[i * 128 + lane], a0);
    a1 = fmaf(hv, W2[i * 128 + 64 + lane], a1);
  }

  // LayerNorm over 128 (two-pass)
  const float mu = wave_allsum(a0 + a1) * (1.0f / 128.0f);
  const float var =
      wave_allsum((a0 - mu) * (a0 - mu) + (a1 - mu) * (a1 - mu)) * (1.0f / 128.0f);
  const float inv = rsqrtf(var + 1e-5f);
  if (act) {
    out[(size_t)row * 128 + lane] = (a0 - mu) * inv * gamma[lane] + beta[lane];
    out[(size_t)row * 128 + 64 + lane] =
        (a1 - mu) * inv * gamma[64 + lane] + beta[64 + lane];
  }
}

// ================= fallback: previous fused single-kernel path =================
__global__ __launch_bounds__(BLK) void prv_kernel(
    const float* __restrict__ x, const float* __restrict__ W1,
    const float* __restrict__ b1, const float* __restrict__ W2,
    const float* __restrict__ b2, const float* __restrict__ gamma,
    const float* __restrict__ beta, float* __restrict__ out, int S) {
  __shared__ float s_row[9000];
  __shared__ float s_peak[NW];
  __shared__ float s_rr[NRR];
  __shared__ float s_red[96];
  __shared__ float s_pow[12];
  __shared__ float s_feat[5];
  __shared__ float s_h1[64];
  __shared__ float s_scr[4];

  const int b = blockIdx.x;
  const int tid = threadIdx.x;
  const float* __restrict__ xrow = x + (size_t)b * S;

  const float4* xr4 = (const float4*)xrow;
  float4* sr4 = (float4*)s_row;
  for (int i = tid; i < S / 4; i += BLK) sr4[i] = xr4[i];
  __syncthreads();

  for (int w = tid; w < NW; w += BLK) {
    const float* p = s_row + w * 15;
    float m = p[0];
#pragma unroll
    for (int j = 1; j < 30; ++j) m = fmaxf(m, p[j]);
    float se = 0.f, we = 0.f;
#pragma unroll
    for (int j = 0; j < 30; ++j) {
      float e = __expf((p[j] - m) * 10.0f);
      se += e;
      we += (float)j * e;
    }
    s_peak[w] = we / se + (float)(w * 15);
  }
  __syncthreads();

  for (int i = tid; i < NRR; i += BLK)
    s_rr[i] = (s_peak[i + 1] - s_peak[i]) * (1.0f / 30.0f);
  __syncthreads();

  float v = 0.f;
  for (int i = tid; i < NRR; i += BLK) v += s_rr[i];
  const float mean_rr = block_sum(v, s_scr, tid) * (1.0f / (float)NRR);

  float sq = 0.f, d2 = 0.f;
  for (int i = tid; i < NRR; i += BLK) {
    float r = s_rr[i] - mean_rr;
    sq += r * r;
    if (i < NRR - 1) {
      float df = s_rr[i + 1] - s_rr[i];
      d2 += df * df;
    }
  }
  const float var_rr = block_sum(sq, s_scr, tid) * (1.0f / (float)(NRR - 1));
  const float msd = block_sum(d2, s_scr, tid) * (1.0f / (float)(NRR - 1));
  const float sdnn = sqrtf(var_rr);
  const float rmssd = sqrtf(msd + 1e-6f);

  float re[12], im[12];
#pragma unroll
  for (int k = 0; k < 12; ++k) { re[k] = 0.f; im[k] = 0.f; }
  for (int n = tid; n < NRR; n += BLK) {
    float rv = s_rr[n];
#pragma unroll
    for (int kk = 0; kk < 12; ++kk) {
      int m = ((kk + 2) * n) & 1023;
      float ang = (float)m * 6.13592315154256491e-3f;
      float sn, cs;
      __sincosf(ang, &sn, &cs);
      re[kk] = fmaf(rv, cs, re[kk]);
      im[kk] = fmaf(-rv, sn, im[kk]);
    }
  }
  const int wid = tid >> 6, lane = tid & 63;
#pragma unroll
  for (int kk = 0; kk < 12; ++kk) {
    float r = wave_sum(re[kk]);
    float i2 = wave_sum(im[kk]);
    if (lane == 0) {
      s_red[wid * 24 + kk] = r;
      s_red[wid * 24 + 12 + kk] = i2;
    }
  }
  __syncthreads();
  if (tid < 12) {
    float r = s_red[tid] + s_red[24 + tid] + s_red[48 + tid] + s_red[72 + tid];
    float i2 =
        s_red[12 + tid] + s_red[36 + tid] + s_red[60 + tid] + s_red[84 + tid];
    s_pow[tid] = r * r + i2 * i2;
  }
  __syncthreads();
  if (tid == 0) {
    float lf = s_pow[0] + s_pow[1] + s_pow[2] + s_pow[3];
    float hf = 0.f;
#pragma unroll
    for (int k = 4; k < 12; ++k) hf += s_pow[k];
    s_feat[0] = mean_rr;
    s_feat[1] = rmssd;
    s_feat[2] = sdnn;
    s_feat[3] = lf;
    s_feat[4] = hf;
  }
  __syncthreads();

  if (tid < 64) {
    float acc = b1[tid];
#pragma unroll
    for (int i = 0; i < 5; ++i) acc = fmaf(s_feat[i], W1[i * 64 + tid], acc);
    s_h1[tid] = fmaxf(acc, 0.f);
  }
  __syncthreads();

  float h2 = 0.f;
  if (tid < 128) {
    float acc = b2[tid];
#pragma unroll 8
    for (int i = 0; i < 64; ++i) acc = fmaf(s_h1[i], W2[i * 128 + tid], acc);
    h2 = acc;
  }

  float sv = (tid < 128) ? h2 : 0.f;
  const float mu = block_sum(sv, s_scr, tid) * (1.0f / 128.0f);
  float dv = (tid < 128) ? (h2 - mu) * (h2 - mu) : 0.f;
  const float var = block_sum(dv, s_scr, tid) * (1.0f / 128.0f);
  if (tid < 128) {
    out[(size_t)b * 128 + tid] =
        (h2 - mu) * rsqrtf(var + 1e-5f) * gamma[tid] + beta[tid];
  }
}

extern "C" void kernel_launch(void* const* d_in, const int* in_sizes, int n_in,
                              void* d_out, int out_size, void* d_ws,
                              size_t ws_size, hipStream_t stream) {
  const float* x = (const float*)d_in[0];
  const float* W1 = (const float*)d_in[1];
  const float* b1 = (const float*)d_in[2];
  const float* W2 = (const float*)d_in[3];
  const float* b2 = (const float*)d_in[4];
  const float* gamma = (const float*)d_in[5];
  const float* beta = (const float*)d_in[6];
  float* out = (float*)d_out;

  const int S = 9000;
  const int B = in_sizes[0] / S;
  const size_t need = (size_t)B * PK_STRIDE * sizeof(float);

  if (ws_size >= need) {
    float* pk = (float*)d_ws;
    dim3 gA(3, B);
    peaks_kernel<<<gA, 256, 0, stream>>>(x, pk);
    feat_kernel<<<(B + 3) / 4, 256, 0, stream>>>(pk, W1, b1, W2, b2, gamma,
                                                 beta, out, B);
  } else {
    prv_kernel<<<B, BLK, 0, stream>>>(x, W1, b1, W2, b2, gamma, beta, out, S);
  }
}